// Round 1
// baseline (258.742 us; speedup 1.0000x reference)
//
#include <hip/hip_runtime.h>
#include <math.h>

#define Bp 256
#define Tp 128
#define SDp 8
#define ADp 2
#define Hp 3
#define Kp 4
#define HIDp 256
#define QDp (SDp + ADp)       // 10
#define X1Dp (Hp * Kp + QDp)  // 22

// ---------------------------------------------------------------------------
// Kernel 1: relative attention -> X1 (B*T, 22) = [x (12) | q_state (10)]
// One 128-thread block per (b, t). Thread j handles neighbor j (j < 127).
// ---------------------------------------------------------------------------
__global__ __launch_bounds__(128) void attn_kernel(
    const float* __restrict__ state, const float* __restrict__ action,
    const float* __restrict__ Wk, const float* __restrict__ Wq,
    const float* __restrict__ Wv, float* __restrict__ X1)
{
    const int bt   = blockIdx.x;
    const int b    = bt >> 7;     // / T
    const int t    = bt & 127;    // % T
    const int tid  = threadIdx.x;
    const int lane = tid & 63;
    const int wave = tid >> 6;

    __shared__ float4 s_lds[Tp];          // state[b, j, 0:4]
    __shared__ float  wq_l[Hp * Kp * QDp];  // 120
    __shared__ float  wk_l[Hp * Kp * Kp];   // 48
    __shared__ float  wv_l[Hp * Kp * Kp];   // 48
    __shared__ float  qs_l[QDp];            // q_state for this (b,t)
    __shared__ float  qkp_l[Hp * Kp];       // [h][c] = sum_k q[h,k]*Wk[h*4+k, c]
    __shared__ float  redA[2][Hp];
    __shared__ float  redB[2][Hp];
    __shared__ float  redX[2][Hp * Kp];

    // stage s rows (state rows are 8 floats; take first 4 as an aligned float4)
    {
        const float4* st4 = (const float4*)(state + (size_t)(b * Tp) * SDp);
        s_lds[tid] = st4[tid * 2];
    }
    for (int i = tid; i < Hp * Kp * QDp; i += 128) wq_l[i] = Wq[i];
    for (int i = tid; i < Hp * Kp * Kp; i += 128) { wk_l[i] = Wk[i]; wv_l[i] = Wv[i]; }
    if (tid < QDp)
        qs_l[tid] = (tid < SDp) ? state[(size_t)bt * SDp + tid]
                                : action[(size_t)bt * ADp + (tid - SDp)];
    __syncthreads();

    // threads 0..11 compute qkp[h][c] (each recomputes q[h,*] locally: 40 FMAs)
    if (tid < Hp * Kp) {
        const int h = tid >> 2, c = tid & 3;
        float acc = 0.f;
        #pragma unroll
        for (int k = 0; k < Kp; ++k) {
            float qhk = 0.f;
            #pragma unroll
            for (int d = 0; d < QDp; ++d) qhk += qs_l[d] * wq_l[(h * Kp + k) * QDp + d];
            acc += qhk * wk_l[(h * Kp + k) * Kp + c];
        }
        qkp_l[tid] = acc;
    }
    __syncthreads();

    float sc[Hp];
    float valr[Hp * Kp];
    #pragma unroll
    for (int h = 0; h < Hp; ++h) sc[h] = -INFINITY;
    #pragma unroll
    for (int r = 0; r < Hp * Kp; ++r) valr[r] = 0.f;

    if (tid < Tp - 1) {
        const int jj = tid + (tid >= t);
        const float4 sj = s_lds[jj];
        const float4 st = s_lds[t];
        float rel[4] = { sj.x - st.x, sj.y - st.y, sj.z - st.z, sj.w - st.w };
        #pragma unroll
        for (int h = 0; h < Hp; ++h) {
            float a = 0.f;
            #pragma unroll
            for (int c = 0; c < Kp; ++c) a += rel[c] * qkp_l[h * Kp + c];
            sc[h] = 0.5f * a;   // / sqrt(K=4)
        }
        #pragma unroll
        for (int r = 0; r < Hp * Kp; ++r) {
            float v = 0.f;
            #pragma unroll
            for (int c = 0; c < Kp; ++c) v += rel[c] * wv_l[r * Kp + c];
            valr[r] = v;
        }
    }

    // ---- softmax max ----
    float m[Hp];
    #pragma unroll
    for (int h = 0; h < Hp; ++h) m[h] = sc[h];
    #pragma unroll
    for (int off = 32; off > 0; off >>= 1)
        #pragma unroll
        for (int h = 0; h < Hp; ++h) m[h] = fmaxf(m[h], __shfl_xor(m[h], off, 64));
    if (lane == 0)
        #pragma unroll
        for (int h = 0; h < Hp; ++h) redA[wave][h] = m[h];
    __syncthreads();
    #pragma unroll
    for (int h = 0; h < Hp; ++h) m[h] = fmaxf(redA[0][h], redA[1][h]);

    // ---- softmax sum ----
    float e[Hp], ssum[Hp];
    #pragma unroll
    for (int h = 0; h < Hp; ++h) {
        e[h] = (tid < Tp - 1) ? __expf(sc[h] - m[h]) : 0.f;
        ssum[h] = e[h];
    }
    #pragma unroll
    for (int off = 32; off > 0; off >>= 1)
        #pragma unroll
        for (int h = 0; h < Hp; ++h) ssum[h] += __shfl_xor(ssum[h], off, 64);
    if (lane == 0)
        #pragma unroll
        for (int h = 0; h < Hp; ++h) redB[wave][h] = ssum[h];
    __syncthreads();
    #pragma unroll
    for (int h = 0; h < Hp; ++h) ssum[h] = redB[0][h] + redB[1][h];

    float w[Hp];
    #pragma unroll
    for (int h = 0; h < Hp; ++h) w[h] = e[h] / ssum[h];

    // ---- weighted value sum ----
    float part[Hp * Kp];
    #pragma unroll
    for (int r = 0; r < Hp * Kp; ++r) part[r] = w[r >> 2] * valr[r];
    #pragma unroll
    for (int off = 32; off > 0; off >>= 1)
        #pragma unroll
        for (int r = 0; r < Hp * Kp; ++r) part[r] += __shfl_xor(part[r], off, 64);
    if (lane == 0)
        #pragma unroll
        for (int r = 0; r < Hp * Kp; ++r) redX[wave][r] = part[r];
    __syncthreads();

    if (tid < Hp * Kp)
        X1[(size_t)bt * X1Dp + tid] = redX[0][tid] + redX[1][tid];
    else if (tid < X1Dp)
        X1[(size_t)bt * X1Dp + tid] = qs_l[tid - Hp * Kp];
}

// ---------------------------------------------------------------------------
// Kernel 2: MLP  X1(22) -> relu 256 -> relu 256 -> 1
// 256 threads per block, 64 positions per block.
// Phase 1: thread n computes h1[p][n] for all 64 p (W1 row in regs).
// Phase 2: thread = (wave -> 16 positions, lane -> 4 output cols), acc[16][4].
// ---------------------------------------------------------------------------
__global__ __launch_bounds__(256) void mlp_kernel(
    const float* __restrict__ X1g, const float* __restrict__ W1,
    const float* __restrict__ b1, const float* __restrict__ W2,
    const float* __restrict__ b2, const float* __restrict__ Wout,
    const float* __restrict__ bout, float* __restrict__ out)
{
    const int tid  = threadIdx.x;
    const int pos0 = blockIdx.x * 64;

    __shared__ __align__(16) float x1[64 * X1Dp];   // 1408 floats
    __shared__ __align__(16) float h1[64 * HIDp];   // 64 KB

    // stage X1 tile (contiguous 1408 floats)
    {
        const float* src = X1g + (size_t)pos0 * X1Dp;
        for (int i = tid; i < 64 * X1Dp; i += 256) x1[i] = src[i];
    }
    __syncthreads();

    // ---- h1 = relu(X1 @ W1.T + b1) ----
    {
        float w1r[X1Dp];
        #pragma unroll
        for (int d = 0; d < X1Dp; ++d) w1r[d] = W1[tid * X1Dp + d];
        const float bb = b1[tid];
        for (int p = 0; p < 64; ++p) {
            float a = bb;
            #pragma unroll
            for (int d = 0; d < X1Dp; ++d) a += x1[p * X1Dp + d] * w1r[d];
            h1[p * HIDp + tid] = fmaxf(a, 0.f);
        }
    }
    __syncthreads();

    // ---- h2 = relu(h1 @ W2.T + b2); out = h2 @ Wout.T + bout ----
    const int wave  = tid >> 6;       // p-group (16 positions)
    const int lane  = tid & 63;       // n-group (4 output cols)
    const int n0    = lane * 4;
    const int pbase = wave * 16;

    float acc[16][4];
    #pragma unroll
    for (int p = 0; p < 16; ++p)
        #pragma unroll
        for (int j = 0; j < 4; ++j) acc[p][j] = 0.f;

    const float4* W2v = (const float4*)W2;
    const float4* h1v = (const float4*)h1;

    for (int k4 = 0; k4 < HIDp / 4; ++k4) {
        const float4 w0 = W2v[(n0 + 0) * 64 + k4];
        const float4 w1_ = W2v[(n0 + 1) * 64 + k4];
        const float4 w2_ = W2v[(n0 + 2) * 64 + k4];
        const float4 w3 = W2v[(n0 + 3) * 64 + k4];
        #pragma unroll
        for (int p = 0; p < 16; ++p) {
            const float4 a = h1v[(pbase + p) * 64 + k4];
            acc[p][0] += a.x * w0.x + a.y * w0.y + a.z * w0.z + a.w * w0.w;
            acc[p][1] += a.x * w1_.x + a.y * w1_.y + a.z * w1_.z + a.w * w1_.w;
            acc[p][2] += a.x * w2_.x + a.y * w2_.y + a.z * w2_.z + a.w * w2_.w;
            acc[p][3] += a.x * w3.x + a.y * w3.y + a.z * w3.z + a.w * w3.w;
        }
    }

    const float4 b2v = ((const float4*)b2)[lane];
    const float4 wov = ((const float4*)Wout)[lane];

    float sums[16];
    #pragma unroll
    for (int p = 0; p < 16; ++p) {
        const float h20 = fmaxf(acc[p][0] + b2v.x, 0.f);
        const float h21 = fmaxf(acc[p][1] + b2v.y, 0.f);
        const float h22 = fmaxf(acc[p][2] + b2v.z, 0.f);
        const float h23 = fmaxf(acc[p][3] + b2v.w, 0.f);
        sums[p] = h20 * wov.x + h21 * wov.y + h22 * wov.z + h23 * wov.w;
    }
    #pragma unroll
    for (int off = 32; off > 0; off >>= 1)
        #pragma unroll
        for (int p = 0; p < 16; ++p) sums[p] += __shfl_xor(sums[p], off, 64);

    if (lane == 0) {
        const float bo = bout[0];
        #pragma unroll
        for (int p = 0; p < 16; ++p) out[pos0 + pbase + p] = sums[p] + bo;
    }
}

extern "C" void kernel_launch(void* const* d_in, const int* in_sizes, int n_in,
                              void* d_out, int out_size, void* d_ws, size_t ws_size,
                              hipStream_t stream) {
    const float* state  = (const float*)d_in[0];
    const float* action = (const float*)d_in[1];
    const float* Wk     = (const float*)d_in[2];
    const float* Wq     = (const float*)d_in[3];
    const float* Wv     = (const float*)d_in[4];
    const float* W1     = (const float*)d_in[5];
    const float* b1     = (const float*)d_in[6];
    const float* W2     = (const float*)d_in[7];
    const float* b2     = (const float*)d_in[8];
    const float* Wout   = (const float*)d_in[9];
    const float* bout   = (const float*)d_in[10];
    float* out = (float*)d_out;
    float* X1  = (float*)d_ws;   // B*T*22 floats = 2.88 MB

    attn_kernel<<<Bp * Tp, 128, 0, stream>>>(state, action, Wk, Wq, Wv, X1);
    mlp_kernel<<<(Bp * Tp) / 64, 256, 0, stream>>>(X1, W1, b1, W2, b2, Wout, bout, out);
}

// Round 2
// 128.452 us; speedup vs baseline: 2.0143x; 2.0143x over previous
//
#include <hip/hip_runtime.h>
#include <math.h>

#define Bp 256
#define Tp 128
#define SDp 8
#define ADp 2
#define Hp 3
#define Kp 4
#define HIDp 256
#define QDp (SDp + ADp)       // 10
#define X1Dp (Hp * Kp + QDp)  // 22  (padded to 32 in bf16 buffer)
#define X1PAD 32
#define H1LD 264              // h1 LDS row stride (bf16) — breaks bank aliasing

typedef short bf16x8 __attribute__((ext_vector_type(8)));
typedef float f32x4  __attribute__((ext_vector_type(4)));

__device__ __forceinline__ unsigned short f2bf(float f) {
    unsigned u = __float_as_uint(f);
    unsigned r = (u + 0x7FFFu + ((u >> 16) & 1u)) >> 16;
    return (unsigned short)r;
}

// ---------------------------------------------------------------------------
// Prep: bf16 copies of W2 (256x256, row-major N x K) and W1 (256x22 -> 256x32
// K-padded). 288 blocks x 256 threads covers 65536 + 8192 elements.
// ---------------------------------------------------------------------------
__global__ __launch_bounds__(256) void prep_kernel(
    const float* __restrict__ W1, const float* __restrict__ W2,
    unsigned short* __restrict__ W1b, unsigned short* __restrict__ W2b)
{
    const int id = blockIdx.x * 256 + threadIdx.x;
    if (id < HIDp * HIDp) {
        W2b[id] = f2bf(W2[id]);
    } else {
        const int i = id - HIDp * HIDp;      // < 8192
        const int r = i >> 5, k = i & 31;
        W1b[i] = (k < X1Dp) ? f2bf(W1[r * X1Dp + k]) : (unsigned short)0;
    }
}

// ---------------------------------------------------------------------------
// Attention (algebraically collapsed): one thread per (b,t), one block per b.
// x[h,:] = (sum_j softmax_hj * s_j  -  s_t) @ Wv_h^T
// Writes X1b rows: [x(12) | q_state(10) | 0-pad(10)] as bf16 (32 per row).
// ---------------------------------------------------------------------------
__global__ __launch_bounds__(128) void attn_kernel(
    const float* __restrict__ state, const float* __restrict__ action,
    const float* __restrict__ Wk, const float* __restrict__ Wq,
    const float* __restrict__ Wv, unsigned short* __restrict__ X1b)
{
    const int b = blockIdx.x;
    const int t = threadIdx.x;

    __shared__ float4 s4[Tp];
    __shared__ float  wq[Hp * Kp * QDp];   // 120
    __shared__ float  wk[Hp * Kp * Kp];    // 48
    __shared__ float  wv[Hp * Kp * Kp];    // 48

    {
        const float4* st4 = (const float4*)(state + (size_t)b * Tp * SDp);
        s4[t] = st4[t * 2];                // first 4 of each 8-float row
    }
    if (t < Hp * Kp * QDp) wq[t] = Wq[t];
    if (t < Hp * Kp * Kp) { wk[t] = Wk[t]; wv[t] = Wv[t]; }
    __syncthreads();

    // q_state for this (b,t)
    float qs[QDp];
    {
        const float* srow = state + ((size_t)b * Tp + t) * SDp;
        #pragma unroll
        for (int d = 0; d < SDp; ++d) qs[d] = srow[d];
        const float* arow = action + ((size_t)b * Tp + t) * ADp;
        qs[8] = arow[0]; qs[9] = arow[1];
    }

    // q = qs @ Wq^T  (12)
    float q[Hp * Kp];
    #pragma unroll
    for (int r = 0; r < Hp * Kp; ++r) {
        float a = 0.f;
        #pragma unroll
        for (int d = 0; d < QDp; ++d) a += qs[d] * wq[r * QDp + d];
        q[r] = a;
    }
    // qkp[h][c] = 0.5 * sum_k q[h,k] * Wk[h*4+k][c]   (0.5 = 1/sqrt(K))
    float qkp[Hp * Kp];
    #pragma unroll
    for (int h = 0; h < Hp; ++h)
        #pragma unroll
        for (int c = 0; c < Kp; ++c) {
            float a = 0.f;
            #pragma unroll
            for (int k = 0; k < Kp; ++k) a += q[h * Kp + k] * wk[(h * Kp + k) * Kp + c];
            qkp[h * Kp + c] = 0.5f * a;
        }

    const float4 st = s4[t];
    float ch[Hp];
    #pragma unroll
    for (int h = 0; h < Hp; ++h)
        ch[h] = st.x * qkp[h*4] + st.y * qkp[h*4+1] + st.z * qkp[h*4+2] + st.w * qkp[h*4+3];

    // softmax-weighted mean of s_j  (no max pass: scores are O(1))
    float l[Hp] = {0.f, 0.f, 0.f};
    float accs[Hp][4] = {};
    for (int j = 0; j < Tp; ++j) {
        const float4 sj = s4[j];
        #pragma unroll
        for (int h = 0; h < Hp; ++h) {
            const float d = sj.x * qkp[h*4] + sj.y * qkp[h*4+1]
                          + sj.z * qkp[h*4+2] + sj.w * qkp[h*4+3] - ch[h];
            const float e = (j == t) ? 0.f : __expf(d);
            l[h] += e;
            accs[h][0] += e * sj.x; accs[h][1] += e * sj.y;
            accs[h][2] += e * sj.z; accs[h][3] += e * sj.w;
        }
    }

    float x[Hp * Kp];
    #pragma unroll
    for (int h = 0; h < Hp; ++h) {
        const float inv = 1.f / l[h];
        const float rb0 = accs[h][0] * inv - st.x;
        const float rb1 = accs[h][1] * inv - st.y;
        const float rb2 = accs[h][2] * inv - st.z;
        const float rb3 = accs[h][3] * inv - st.w;
        #pragma unroll
        for (int k = 0; k < Kp; ++k) {
            const int r = h * Kp + k;
            x[r] = rb0 * wv[r*4] + rb1 * wv[r*4+1] + rb2 * wv[r*4+2] + rb3 * wv[r*4+3];
        }
    }

    unsigned short rowb[X1PAD];
    #pragma unroll
    for (int i = 0; i < Hp * Kp; ++i) rowb[i] = f2bf(x[i]);
    #pragma unroll
    for (int i = 0; i < QDp; ++i) rowb[Hp * Kp + i] = f2bf(qs[i]);
    #pragma unroll
    for (int i = X1Dp; i < X1PAD; ++i) rowb[i] = 0;

    uint4* dst = (uint4*)(X1b + ((size_t)b * Tp + t) * X1PAD);
    const uint4* srcv = (const uint4*)rowb;
    #pragma unroll
    for (int i = 0; i < 4; ++i) dst[i] = srcv[i];
}

// ---------------------------------------------------------------------------
// MLP via MFMA: 64 positions/block, 4 waves (wave = 16-row m-tile).
// MLP1: K=32 (padded), 1 mfma per n-tile.  h1 -> LDS bf16 (stride H1LD).
// MLP2: A-frags register-resident (8), B streamed from L2-resident W2b.
// Epilogue fuses relu+b2, Wout dot, cross-lane reduce, store.
// ---------------------------------------------------------------------------
__global__ __launch_bounds__(256, 2) void mlp_kernel(
    const unsigned short* __restrict__ X1b, const unsigned short* __restrict__ W1b,
    const unsigned short* __restrict__ W2b,
    const float* __restrict__ b1, const float* __restrict__ b2,
    const float* __restrict__ Wout, const float* __restrict__ bout,
    float* __restrict__ out)
{
    const int tid  = threadIdx.x;
    const int lane = tid & 63;
    const int wave = tid >> 6;
    const int quad = lane >> 4;
    const int l16  = lane & 15;
    const int pos0 = blockIdx.x * 64;

    __shared__ __align__(16) unsigned short x1s[64 * X1PAD];    // 4 KB
    __shared__ __align__(16) unsigned short w1s[HIDp * X1PAD];  // 16 KB
    __shared__ __align__(16) unsigned short h1s[64 * H1LD];     // 33.8 KB

    // stage X1 tile (64*32 ushort = 256 uint4) and W1b (1024 uint4)
    {
        const uint4* src = (const uint4*)(X1b + (size_t)pos0 * X1PAD);
        ((uint4*)x1s)[tid] = src[tid];
        const uint4* w1v = (const uint4*)W1b;
        uint4* dst = (uint4*)w1s;
        #pragma unroll
        for (int i = 0; i < 4; ++i) dst[tid + i * 256] = w1v[tid + i * 256];
    }
    __syncthreads();

    // ---- MLP1: h1 = relu(X1 @ W1^T + b1) ----
    {
        const bf16x8 afr = *(const bf16x8*)&x1s[(wave * 16 + l16) * X1PAD + quad * 8];
        for (int nt = 0; nt < 16; ++nt) {
            const bf16x8 bfr = *(const bf16x8*)&w1s[(nt * 16 + l16) * X1PAD + quad * 8];
            f32x4 acc = {0.f, 0.f, 0.f, 0.f};
            acc = __builtin_amdgcn_mfma_f32_16x16x32_bf16(afr, bfr, acc, 0, 0, 0);
            const int col = nt * 16 + l16;
            const float bb = b1[col];
            #pragma unroll
            for (int r = 0; r < 4; ++r) {
                const int row = wave * 16 + quad * 4 + r;
                h1s[row * H1LD + col] = f2bf(fmaxf(acc[r] + bb, 0.f));
            }
        }
    }
    __syncthreads();

    // ---- MLP2 + out: h2 = relu(h1 @ W2^T + b2); out = h2 @ Wout^T + bout ----
    bf16x8 A[8];
    #pragma unroll
    for (int ks = 0; ks < 8; ++ks)
        A[ks] = *(const bf16x8*)&h1s[(wave * 16 + l16) * H1LD + ks * 32 + quad * 8];

    float rsum[4] = {0.f, 0.f, 0.f, 0.f};
    for (int nt = 0; nt < 16; ++nt) {
        const int col = nt * 16 + l16;
        const unsigned short* wrow = W2b + (size_t)col * HIDp + quad * 8;
        bf16x8 Bf[8];
        #pragma unroll
        for (int ks = 0; ks < 8; ++ks)
            Bf[ks] = *(const bf16x8*)(wrow + ks * 32);
        f32x4 acc = {0.f, 0.f, 0.f, 0.f};
        #pragma unroll
        for (int ks = 0; ks < 8; ++ks)
            acc = __builtin_amdgcn_mfma_f32_16x16x32_bf16(A[ks], Bf[ks], acc, 0, 0, 0);
        const float bb = b2[col];
        const float wo = Wout[col];
        #pragma unroll
        for (int r = 0; r < 4; ++r)
            rsum[r] += fmaxf(acc[r] + bb, 0.f) * wo;
    }

    // reduce over the 16 cols held per quad (lanes sharing quad -> same rows)
    #pragma unroll
    for (int off = 1; off < 16; off <<= 1)
        #pragma unroll
        for (int r = 0; r < 4; ++r)
            rsum[r] += __shfl_xor(rsum[r], off, 64);

    if (l16 == 0) {
        const float bo = bout[0];
        #pragma unroll
        for (int r = 0; r < 4; ++r)
            out[pos0 + wave * 16 + quad * 4 + r] = rsum[r] + bo;
    }
}

extern "C" void kernel_launch(void* const* d_in, const int* in_sizes, int n_in,
                              void* d_out, int out_size, void* d_ws, size_t ws_size,
                              hipStream_t stream) {
    const float* state  = (const float*)d_in[0];
    const float* action = (const float*)d_in[1];
    const float* Wk     = (const float*)d_in[2];
    const float* Wq     = (const float*)d_in[3];
    const float* Wv     = (const float*)d_in[4];
    const float* W1     = (const float*)d_in[5];
    const float* b1     = (const float*)d_in[6];
    const float* W2     = (const float*)d_in[7];
    const float* b2     = (const float*)d_in[8];
    const float* Wout   = (const float*)d_in[9];
    const float* bout   = (const float*)d_in[10];
    float* out = (float*)d_out;

    char* ws = (char*)d_ws;
    unsigned short* W1b = (unsigned short*)(ws);                 // 16 KB
    unsigned short* W2b = (unsigned short*)(ws + 16384);         // 128 KB
    unsigned short* X1b = (unsigned short*)(ws + 16384 + 131072);// 2 MB

    prep_kernel<<<288, 256, 0, stream>>>(W1, W2, W1b, W2b);
    attn_kernel<<<Bp, Tp, 0, stream>>>(state, action, Wk, Wq, Wv, X1b);
    mlp_kernel<<<(Bp * Tp) / 64, 256, 0, stream>>>(X1b, W1b, W2b, b1, b2, Wout, bout, out);
}

// Round 3
// 124.803 us; speedup vs baseline: 2.0732x; 1.0292x over previous
//
#include <hip/hip_runtime.h>
#include <math.h>

#define Bp 256
#define Tp 128
#define SDp 8
#define ADp 2
#define Hp 3
#define Kp 4
#define HIDp 256
#define QDp (SDp + ADp)       // 10
#define X1Dp (Hp * Kp + QDp)  // 22  (padded to 32 in bf16 buffer)
#define X1PAD 32
#define H1LD 264              // h1 LDS row stride (bf16)

typedef short bf16x8 __attribute__((ext_vector_type(8)));
typedef float f32x4  __attribute__((ext_vector_type(4)));

__device__ __forceinline__ unsigned short f2bf(float f) {
    unsigned u = __float_as_uint(f);
    unsigned r = (u + 0x7FFFu + ((u >> 16) & 1u)) >> 16;
    return (unsigned short)r;
}

// ---------------------------------------------------------------------------
// Fused: blocks [0,128) = attention (2 batches per block, 256 threads);
//        blocks [128,200) = weight bf16 prep (4 elements per thread).
// attn (collapsed): x[h,:] = (sum_j softmax_hj * s_j - s_t) @ Wv_h^T
// X1b row: [x(12) | q_state(10) | 0(10)] bf16.
// ---------------------------------------------------------------------------
__global__ __launch_bounds__(256) void attn_prep_kernel(
    const float* __restrict__ state, const float* __restrict__ action,
    const float* __restrict__ Wk, const float* __restrict__ Wq,
    const float* __restrict__ Wv, const float* __restrict__ W1,
    const float* __restrict__ W2, unsigned short* __restrict__ W1b,
    unsigned short* __restrict__ W2b, unsigned short* __restrict__ X1b)
{
    if (blockIdx.x >= 128) {
        // ---- prep: 72 blocks * 256 threads * 4 elems = 73728 = 65536 + 8192
        const int id0 = (blockIdx.x - 128) * 1024 + threadIdx.x * 4;
        if (id0 < HIDp * HIDp) {
            const float4 v = *(const float4*)(W2 + id0);
            ushort4 o;
            o.x = f2bf(v.x); o.y = f2bf(v.y); o.z = f2bf(v.z); o.w = f2bf(v.w);
            *(ushort4*)(W2b + id0) = o;
        } else {
            #pragma unroll
            for (int u = 0; u < 4; ++u) {
                const int i = id0 - HIDp * HIDp + u;
                const int r = i >> 5, k = i & 31;
                W1b[i] = (k < X1Dp) ? f2bf(W1[r * X1Dp + k]) : (unsigned short)0;
            }
        }
        return;
    }

    // ---- attention ----
    const int half = threadIdx.x >> 7;
    const int t    = threadIdx.x & 127;
    const int b    = blockIdx.x * 2 + half;

    __shared__ float4 s4[2][Tp];
    __shared__ float  wq[Hp * Kp * QDp];   // 120
    __shared__ float  wk[Hp * Kp * Kp];    // 48
    __shared__ float  wv[Hp * Kp * Kp];    // 48

    s4[half][t] = ((const float4*)(state + (size_t)b * Tp * SDp))[t * 2];
    if (threadIdx.x < Hp * Kp * QDp) wq[threadIdx.x] = Wq[threadIdx.x];
    if (threadIdx.x < Hp * Kp * Kp) { wk[threadIdx.x] = Wk[threadIdx.x]; wv[threadIdx.x] = Wv[threadIdx.x]; }
    __syncthreads();

    float qs[QDp];
    {
        const float* srow = state + ((size_t)b * Tp + t) * SDp;
        #pragma unroll
        for (int d = 0; d < SDp; ++d) qs[d] = srow[d];
        const float* arow = action + ((size_t)b * Tp + t) * ADp;
        qs[8] = arow[0]; qs[9] = arow[1];
    }

    float q[Hp * Kp];
    #pragma unroll
    for (int r = 0; r < Hp * Kp; ++r) {
        float a = 0.f;
        #pragma unroll
        for (int d = 0; d < QDp; ++d) a += qs[d] * wq[r * QDp + d];
        q[r] = a;
    }
    float qkp[Hp * Kp];
    #pragma unroll
    for (int h = 0; h < Hp; ++h)
        #pragma unroll
        for (int c = 0; c < Kp; ++c) {
            float a = 0.f;
            #pragma unroll
            for (int k = 0; k < Kp; ++k) a += q[h * Kp + k] * wk[(h * Kp + k) * Kp + c];
            qkp[h * Kp + c] = 0.5f * a;   // 1/sqrt(K=4)
        }

    const float4 st = s4[half][t];
    float ch[Hp];
    #pragma unroll
    for (int h = 0; h < Hp; ++h)
        ch[h] = st.x * qkp[h*4] + st.y * qkp[h*4+1] + st.z * qkp[h*4+2] + st.w * qkp[h*4+3];

    float l[Hp] = {0.f, 0.f, 0.f};
    float accs[Hp][4] = {};
    for (int j = 0; j < Tp; ++j) {
        const float4 sj = s4[half][j];
        #pragma unroll
        for (int h = 0; h < Hp; ++h) {
            const float d = sj.x * qkp[h*4] + sj.y * qkp[h*4+1]
                          + sj.z * qkp[h*4+2] + sj.w * qkp[h*4+3] - ch[h];
            const float e = (j == t) ? 0.f : __expf(d);
            l[h] += e;
            accs[h][0] += e * sj.x; accs[h][1] += e * sj.y;
            accs[h][2] += e * sj.z; accs[h][3] += e * sj.w;
        }
    }

    unsigned short rowb[X1PAD];
    #pragma unroll
    for (int h = 0; h < Hp; ++h) {
        const float inv = 1.f / l[h];
        const float rb0 = accs[h][0] * inv - st.x;
        const float rb1 = accs[h][1] * inv - st.y;
        const float rb2 = accs[h][2] * inv - st.z;
        const float rb3 = accs[h][3] * inv - st.w;
        #pragma unroll
        for (int k = 0; k < Kp; ++k) {
            const int r = h * Kp + k;
            rowb[r] = f2bf(rb0 * wv[r*4] + rb1 * wv[r*4+1] + rb2 * wv[r*4+2] + rb3 * wv[r*4+3]);
        }
    }
    #pragma unroll
    for (int i = 0; i < QDp; ++i) rowb[Hp * Kp + i] = f2bf(qs[i]);
    #pragma unroll
    for (int i = X1Dp; i < X1PAD; ++i) rowb[i] = 0;

    uint4* dst = (uint4*)(X1b + ((size_t)b * Tp + t) * X1PAD);
    const uint4* srcv = (const uint4*)rowb;
    #pragma unroll
    for (int i = 0; i < 4; ++i) dst[i] = srcv[i];
}

// ---------------------------------------------------------------------------
// MLP via MFMA, slim: 64 positions/block, 4 waves. LDS = h1 only (33.8 KB,
// 4 blocks/CU). A-frags and W1/W2 B-frags read straight from global (L2-hot,
// 1KB-contiguous per wave for X1b/W1b). One barrier.
// ---------------------------------------------------------------------------
__global__ __launch_bounds__(256, 4) void mlp_kernel(
    const unsigned short* __restrict__ X1b, const unsigned short* __restrict__ W1b,
    const unsigned short* __restrict__ W2b,
    const float* __restrict__ b1, const float* __restrict__ b2,
    const float* __restrict__ Wout, const float* __restrict__ bout,
    float* __restrict__ out)
{
    const int tid  = threadIdx.x;
    const int lane = tid & 63;
    const int wave = tid >> 6;
    const int quad = lane >> 4;
    const int l16  = lane & 15;
    const int pos0 = blockIdx.x * 64;

    __shared__ __align__(16) unsigned short h1s[64 * H1LD];   // 33.8 KB

    // ---- MLP1: h1 = relu(X1 @ W1^T + b1) -> LDS (bf16) ----
    {
        const bf16x8 afr = *(const bf16x8*)&X1b[((size_t)pos0 + wave * 16 + l16) * X1PAD + quad * 8];
        for (int nt = 0; nt < 16; ++nt) {
            const bf16x8 bfr = *(const bf16x8*)&W1b[(nt * 16 + l16) * X1PAD + quad * 8];
            f32x4 acc = {0.f, 0.f, 0.f, 0.f};
            acc = __builtin_amdgcn_mfma_f32_16x16x32_bf16(afr, bfr, acc, 0, 0, 0);
            const int col = nt * 16 + l16;
            const float bb = b1[col];
            #pragma unroll
            for (int r = 0; r < 4; ++r)
                h1s[(wave * 16 + quad * 4 + r) * H1LD + col] = f2bf(fmaxf(acc[r] + bb, 0.f));
        }
    }
    __syncthreads();

    // ---- MLP2 + out ----
    bf16x8 A[8];
    #pragma unroll
    for (int ks = 0; ks < 8; ++ks)
        A[ks] = *(const bf16x8*)&h1s[(wave * 16 + l16) * H1LD + ks * 32 + quad * 8];

    float rsum[4] = {0.f, 0.f, 0.f, 0.f};
    for (int nt = 0; nt < 16; ++nt) {
        const int col = nt * 16 + l16;
        const unsigned short* wrow = W2b + (size_t)col * HIDp + quad * 8;
        bf16x8 Bf[8];
        #pragma unroll
        for (int ks = 0; ks < 8; ++ks)
            Bf[ks] = *(const bf16x8*)(wrow + ks * 32);
        f32x4 acc = {0.f, 0.f, 0.f, 0.f};
        #pragma unroll
        for (int ks = 0; ks < 8; ++ks)
            acc = __builtin_amdgcn_mfma_f32_16x16x32_bf16(A[ks], Bf[ks], acc, 0, 0, 0);
        const float bb = b2[col];
        const float wo = Wout[col];
        #pragma unroll
        for (int r = 0; r < 4; ++r)
            rsum[r] += fmaxf(acc[r] + bb, 0.f) * wo;
    }

    #pragma unroll
    for (int off = 1; off < 16; off <<= 1)
        #pragma unroll
        for (int r = 0; r < 4; ++r)
            rsum[r] += __shfl_xor(rsum[r], off, 64);

    if (l16 == 0) {
        const float bo = bout[0];
        #pragma unroll
        for (int r = 0; r < 4; ++r)
            out[pos0 + wave * 16 + quad * 4 + r] = rsum[r] + bo;
    }
}

extern "C" void kernel_launch(void* const* d_in, const int* in_sizes, int n_in,
                              void* d_out, int out_size, void* d_ws, size_t ws_size,
                              hipStream_t stream) {
    const float* state  = (const float*)d_in[0];
    const float* action = (const float*)d_in[1];
    const float* Wk     = (const float*)d_in[2];
    const float* Wq     = (const float*)d_in[3];
    const float* Wv     = (const float*)d_in[4];
    const float* W1     = (const float*)d_in[5];
    const float* b1     = (const float*)d_in[6];
    const float* W2     = (const float*)d_in[7];
    const float* b2     = (const float*)d_in[8];
    const float* Wout   = (const float*)d_in[9];
    const float* bout   = (const float*)d_in[10];
    float* out = (float*)d_out;

    char* ws = (char*)d_ws;
    unsigned short* W1b = (unsigned short*)(ws);                  // 16 KB
    unsigned short* W2b = (unsigned short*)(ws + 16384);          // 128 KB
    unsigned short* X1b = (unsigned short*)(ws + 16384 + 131072); // 2 MB

    attn_prep_kernel<<<200, 256, 0, stream>>>(state, action, Wk, Wq, Wv, W1, W2,
                                              W1b, W2b, X1b);
    mlp_kernel<<<(Bp * Tp) / 64, 256, 0, stream>>>(X1b, W1b, W2b, b1, b2, Wout, bout, out);
}

// Round 4
// 122.044 us; speedup vs baseline: 2.1201x; 1.0226x over previous
//
#include <hip/hip_runtime.h>
#include <math.h>

#define Bp 256
#define Tp 128
#define SDp 8
#define ADp 2
#define Hp 3
#define Kp 4
#define HIDp 256
#define QDp (SDp + ADp)       // 10
#define X1Dp (Hp * Kp + QDp)  // 22  (padded to 32 in bf16 buffer)
#define X1PAD 32
#define H1LD 264              // h1 LDS row stride (bf16)
#define LOG2E 1.4426950408889634f

typedef short bf16x8 __attribute__((ext_vector_type(8)));
typedef float f32x4  __attribute__((ext_vector_type(4)));

__device__ __forceinline__ unsigned short f2bf(float f) {
    unsigned u = __float_as_uint(f);
    unsigned r = (u + 0x7FFFu + ((u >> 16) & 1u)) >> 16;
    return (unsigned short)r;
}

// ---------------------------------------------------------------------------
// Fused: blocks [0,256) = attention (1 batch per block, 2 threads per t —
//        each covers half the j-range, combined in LDS);
//        blocks [256,328) = weight bf16 prep (4 elements per thread).
// attn (collapsed): x[h,:] = (sum_j softmax_hj * s_j - s_t) @ Wv_h^T
// exp folded to exp2 by prescaling qkp/ch with log2(e).
// X1b row: [x(12) | q_state(10) | 0(10)] bf16.
// ---------------------------------------------------------------------------
__global__ __launch_bounds__(256) void attn_prep_kernel(
    const float* __restrict__ state, const float* __restrict__ action,
    const float* __restrict__ Wk, const float* __restrict__ Wq,
    const float* __restrict__ Wv, const float* __restrict__ W1,
    const float* __restrict__ W2, unsigned short* __restrict__ W1b,
    unsigned short* __restrict__ W2b, unsigned short* __restrict__ X1b)
{
    if (blockIdx.x >= Bp) {
        // ---- prep: 72 blocks * 256 threads * 4 elems = 73728 = 65536 + 8192
        const int id0 = (blockIdx.x - Bp) * 1024 + threadIdx.x * 4;
        if (id0 < HIDp * HIDp) {
            const float4 v = *(const float4*)(W2 + id0);
            ushort4 o;
            o.x = f2bf(v.x); o.y = f2bf(v.y); o.z = f2bf(v.z); o.w = f2bf(v.w);
            *(ushort4*)(W2b + id0) = o;
        } else {
            #pragma unroll
            for (int u = 0; u < 4; ++u) {
                const int i = id0 - HIDp * HIDp + u;
                const int r = i >> 5, k = i & 31;
                W1b[i] = (k < X1Dp) ? f2bf(W1[r * X1Dp + k]) : (unsigned short)0;
            }
        }
        return;
    }

    // ---- attention: b = blockIdx.x; thread = (t, jh) ----
    const int b  = blockIdx.x;
    const int t  = threadIdx.x & 127;
    const int jh = threadIdx.x >> 7;   // 0: j in [0,64), 1: j in [64,128)

    __shared__ float4 s4[Tp];
    __shared__ float  wq[Hp * Kp * QDp];   // 120
    __shared__ float  wk[Hp * Kp * Kp];    // 48
    __shared__ float  wv[Hp * Kp * Kp];    // 48
    __shared__ float  part[Tp][16];        // l[3] + accs[12], 8 KB

    if (threadIdx.x < Tp)
        s4[threadIdx.x] = ((const float4*)(state + (size_t)b * Tp * SDp))[threadIdx.x * 2];
    if (threadIdx.x >= Tp && threadIdx.x < Tp + Hp * Kp * QDp)
        wq[threadIdx.x - Tp] = Wq[threadIdx.x - Tp];
    if (threadIdx.x < Hp * Kp * Kp) { wk[threadIdx.x] = Wk[threadIdx.x]; wv[threadIdx.x] = Wv[threadIdx.x]; }
    __syncthreads();

    float qs[QDp];
    {
        const float* srow = state + ((size_t)b * Tp + t) * SDp;
        #pragma unroll
        for (int d = 0; d < SDp; ++d) qs[d] = srow[d];
        const float* arow = action + ((size_t)b * Tp + t) * ADp;
        qs[8] = arow[0]; qs[9] = arow[1];
    }

    float q[Hp * Kp];
    #pragma unroll
    for (int r = 0; r < Hp * Kp; ++r) {
        float a = 0.f;
        #pragma unroll
        for (int d = 0; d < QDp; ++d) a += qs[d] * wq[r * QDp + d];
        q[r] = a;
    }
    // qkp[h][c] = (0.5 * log2e) * sum_k q[h,k] * Wk[h*4+k][c]
    float qkp[Hp * Kp];
    #pragma unroll
    for (int h = 0; h < Hp; ++h)
        #pragma unroll
        for (int c = 0; c < Kp; ++c) {
            float a = 0.f;
            #pragma unroll
            for (int k = 0; k < Kp; ++k) a += q[h * Kp + k] * wk[(h * Kp + k) * Kp + c];
            qkp[h * Kp + c] = 0.5f * LOG2E * a;
        }

    const float4 st = s4[t];
    float ch[Hp];
    #pragma unroll
    for (int h = 0; h < Hp; ++h)
        ch[h] = st.x * qkp[h*4] + st.y * qkp[h*4+1] + st.z * qkp[h*4+2] + st.w * qkp[h*4+3];

    float l[Hp] = {0.f, 0.f, 0.f};
    float accs[Hp][4] = {};
    const int j0 = jh * 64;
    for (int j = j0; j < j0 + 64; ++j) {
        const float4 sj = s4[j];
        #pragma unroll
        for (int h = 0; h < Hp; ++h) {
            const float d = sj.x * qkp[h*4] + sj.y * qkp[h*4+1]
                          + sj.z * qkp[h*4+2] + sj.w * qkp[h*4+3] - ch[h];
            const float e = (j == t) ? 0.f : exp2f(d);
            l[h] += e;
            accs[h][0] += e * sj.x; accs[h][1] += e * sj.y;
            accs[h][2] += e * sj.z; accs[h][3] += e * sj.w;
        }
    }

    if (jh == 1) {
        #pragma unroll
        for (int h = 0; h < Hp; ++h) {
            part[t][h] = l[h];
            #pragma unroll
            for (int c = 0; c < Kp; ++c) part[t][3 + h * 4 + c] = accs[h][c];
        }
    }
    __syncthreads();

    if (jh == 0) {
        unsigned short rowb[X1PAD];
        #pragma unroll
        for (int h = 0; h < Hp; ++h) {
            const float lt = l[h] + part[t][h];
            const float inv = 1.f / lt;
            const float rb0 = (accs[h][0] + part[t][3 + h*4 + 0]) * inv - st.x;
            const float rb1 = (accs[h][1] + part[t][3 + h*4 + 1]) * inv - st.y;
            const float rb2 = (accs[h][2] + part[t][3 + h*4 + 2]) * inv - st.z;
            const float rb3 = (accs[h][3] + part[t][3 + h*4 + 3]) * inv - st.w;
            #pragma unroll
            for (int k = 0; k < Kp; ++k) {
                const int r = h * Kp + k;
                rowb[r] = f2bf(rb0 * wv[r*4] + rb1 * wv[r*4+1] + rb2 * wv[r*4+2] + rb3 * wv[r*4+3]);
            }
        }
        #pragma unroll
        for (int i = 0; i < QDp; ++i) rowb[Hp * Kp + i] = f2bf(qs[i]);
        #pragma unroll
        for (int i = X1Dp; i < X1PAD; ++i) rowb[i] = 0;

        uint4* dst = (uint4*)(X1b + ((size_t)b * Tp + t) * X1PAD);
        const uint4* srcv = (const uint4*)rowb;
        #pragma unroll
        for (int i = 0; i < 4; ++i) dst[i] = srcv[i];
    }
}

// ---------------------------------------------------------------------------
// MLP via MFMA: 64 positions/block, 4 waves. LDS = h1 only (33.8 KB,
// 4 blocks/CU). A-frags and W1/W2 B-frags read straight from global (L2-hot).
// ---------------------------------------------------------------------------
__global__ __launch_bounds__(256, 4) void mlp_kernel(
    const unsigned short* __restrict__ X1b, const unsigned short* __restrict__ W1b,
    const unsigned short* __restrict__ W2b,
    const float* __restrict__ b1, const float* __restrict__ b2,
    const float* __restrict__ Wout, const float* __restrict__ bout,
    float* __restrict__ out)
{
    const int tid  = threadIdx.x;
    const int lane = tid & 63;
    const int wave = tid >> 6;
    const int quad = lane >> 4;
    const int l16  = lane & 15;
    const int pos0 = blockIdx.x * 64;

    __shared__ __align__(16) unsigned short h1s[64 * H1LD];   // 33.8 KB

    // ---- MLP1: h1 = relu(X1 @ W1^T + b1) -> LDS (bf16) ----
    {
        const bf16x8 afr = *(const bf16x8*)&X1b[((size_t)pos0 + wave * 16 + l16) * X1PAD + quad * 8];
        for (int nt = 0; nt < 16; ++nt) {
            const bf16x8 bfr = *(const bf16x8*)&W1b[(nt * 16 + l16) * X1PAD + quad * 8];
            f32x4 acc = {0.f, 0.f, 0.f, 0.f};
            acc = __builtin_amdgcn_mfma_f32_16x16x32_bf16(afr, bfr, acc, 0, 0, 0);
            const int col = nt * 16 + l16;
            const float bb = b1[col];
            #pragma unroll
            for (int r = 0; r < 4; ++r)
                h1s[(wave * 16 + quad * 4 + r) * H1LD + col] = f2bf(fmaxf(acc[r] + bb, 0.f));
        }
    }
    __syncthreads();

    // ---- MLP2 + out ----
    bf16x8 A[8];
    #pragma unroll
    for (int ks = 0; ks < 8; ++ks)
        A[ks] = *(const bf16x8*)&h1s[(wave * 16 + l16) * H1LD + ks * 32 + quad * 8];

    float rsum[4] = {0.f, 0.f, 0.f, 0.f};
    for (int nt = 0; nt < 16; ++nt) {
        const int col = nt * 16 + l16;
        const unsigned short* wrow = W2b + (size_t)col * HIDp + quad * 8;
        bf16x8 Bf[8];
        #pragma unroll
        for (int ks = 0; ks < 8; ++ks)
            Bf[ks] = *(const bf16x8*)(wrow + ks * 32);
        f32x4 acc = {0.f, 0.f, 0.f, 0.f};
        #pragma unroll
        for (int ks = 0; ks < 8; ++ks)
            acc = __builtin_amdgcn_mfma_f32_16x16x32_bf16(A[ks], Bf[ks], acc, 0, 0, 0);
        const float bb = b2[col];
        const float wo = Wout[col];
        #pragma unroll
        for (int r = 0; r < 4; ++r)
            rsum[r] += fmaxf(acc[r] + bb, 0.f) * wo;
    }

    #pragma unroll
    for (int off = 1; off < 16; off <<= 1)
        #pragma unroll
        for (int r = 0; r < 4; ++r)
            rsum[r] += __shfl_xor(rsum[r], off, 64);

    if (l16 == 0) {
        const float bo = bout[0];
        #pragma unroll
        for (int r = 0; r < 4; ++r)
            out[pos0 + wave * 16 + quad * 4 + r] = rsum[r] + bo;
    }
}

extern "C" void kernel_launch(void* const* d_in, const int* in_sizes, int n_in,
                              void* d_out, int out_size, void* d_ws, size_t ws_size,
                              hipStream_t stream) {
    const float* state  = (const float*)d_in[0];
    const float* action = (const float*)d_in[1];
    const float* Wk     = (const float*)d_in[2];
    const float* Wq     = (const float*)d_in[3];
    const float* Wv     = (const float*)d_in[4];
    const float* W1     = (const float*)d_in[5];
    const float* b1     = (const float*)d_in[6];
    const float* W2     = (const float*)d_in[7];
    const float* b2     = (const float*)d_in[8];
    const float* Wout   = (const float*)d_in[9];
    const float* bout   = (const float*)d_in[10];
    float* out = (float*)d_out;

    char* ws = (char*)d_ws;
    unsigned short* W1b = (unsigned short*)(ws);                  // 16 KB
    unsigned short* W2b = (unsigned short*)(ws + 16384);          // 128 KB
    unsigned short* X1b = (unsigned short*)(ws + 16384 + 131072); // 2 MB

    attn_prep_kernel<<<Bp + 72, 256, 0, stream>>>(state, action, Wk, Wq, Wv, W1, W2,
                                                  W1b, W2b, X1b);
    mlp_kernel<<<(Bp * Tp) / 64, 256, 0, stream>>>(X1b, W1b, W2b, b1, b2, Wout, bout, out);
}